// Round 4
// baseline (1582.773 us; speedup 1.0000x reference)
//
#include <hip/hip_runtime.h>
#include <math.h>

namespace {

constexpr int Sq = 43;
constexpr int Dm = 18;
constexpr int Dff = 2048;
constexpr int Am = 128;
constexpr int Nb = 7;
constexpr int NR = 11008;          // B*SEQ rows
constexpr int RSZ = NR * Dm;       // 198144 floats
constexpr int JC = 8;              // j-chunks in FFN (256 j each)
constexpr float EPSf = 1e-6f;

// ---------------------------------------------------------------------------
// LN1 + QKV projection for one row (y[18] in registers), writes q/k/v rows.
// ---------------------------------------------------------------------------
__device__ __forceinline__ void ln_qkv_write(
    int row, const float* y, int ly,
    const float* __restrict__ Wq, const float* __restrict__ bq,
    const float* __restrict__ Wk, const float* __restrict__ bk,
    const float* __restrict__ Wv, const float* __restrict__ bv,
    const float* __restrict__ ln1a, const float* __restrict__ ln1b,
    float* __restrict__ qb, float* __restrict__ kb, float* __restrict__ vb)
{
    float mu = 0.f;
    #pragma unroll
    for (int d = 0; d < Dm; d++) mu += y[d];
    mu *= (1.f / Dm);
    float var = 0.f;
    #pragma unroll
    for (int d = 0; d < Dm; d++) { float t = y[d] - mu; var += t * t; }
    var *= (1.f / (Dm - 1));                 // ddof=1
    float isd = 1.f / (sqrtf(var) + EPSf);   // eps on sd
    float x2[Dm];
    #pragma unroll
    for (int d = 0; d < Dm; d++)
        x2[d] = ln1a[ly * Dm + d] * (y[d] - mu) * isd + ln1b[ly * Dm + d];
    const float* wq = Wq + ly * Dm * Dm;
    const float* wk = Wk + ly * Dm * Dm;
    const float* wv = Wv + ly * Dm * Dm;
    #pragma unroll 3
    for (int d = 0; d < Dm; d++) {
        float aq = bq[ly * Dm + d];
        float ak = bk[ly * Dm + d];
        float av = bv[ly * Dm + d];
        #pragma unroll
        for (int dd = 0; dd < Dm; dd++) {
            aq += x2[dd] * wq[dd * Dm + d];
            ak += x2[dd] * wk[dd * Dm + d];
            av += x2[dd] * wv[dd * Dm + d];
        }
        qb[(size_t)row * Dm + d] = aq;
        kb[(size_t)row * Dm + d] = ak;
        vb[(size_t)row * Dm + d] = av;
    }
}

// ---------------------------------------------------------------------------
// k_init: blocks 0..171 = rows (64 each); block 172 = tail precompute (prep).
// ---------------------------------------------------------------------------
__global__ __launch_bounds__(64) void k_init(
    const float* __restrict__ src, float* __restrict__ xg,
    const float* __restrict__ Wq, const float* __restrict__ bq,
    const float* __restrict__ Wk, const float* __restrict__ bk,
    const float* __restrict__ Wv, const float* __restrict__ bv,
    const float* __restrict__ ln1a, const float* __restrict__ ln1b,
    float* __restrict__ qb, float* __restrict__ kb, float* __restrict__ vb,
    const float* __restrict__ llW, const float* __restrict__ llb,
    const float* __restrict__ flW, const float* __restrict__ flb,
    const float* __restrict__ ll2b,
    float* __restrict__ Mw, float* __restrict__ PS1, float* __restrict__ QS2)
{
    __shared__ float M[602];
    __shared__ float cc2[14];
    __shared__ float SS[14];
    const int tid = threadIdx.x;

    if (blockIdx.x == 172) {
        // ---- tail precompute ----
        for (int m = tid; m < 602; m += 64) {
            int half = m / 301, rem = m - half * 301;
            int s = rem / 7, n = rem - 7 * s;
            float a = 0.f;
            for (int jj = 0; jj < Am; jj++)
                a += llW[s * Am + jj] * flW[(half * Am + jj) * Nb + n];
            M[m] = a;
        }
        if (tid < 14) {
            int half = tid / 7, n = tid - 7 * (tid / 7);
            float a = 0.f;
            for (int jj = 0; jj < Am; jj++)
                a += llb[jj] * flW[(half * Am + jj) * Nb + n];
            cc2[tid] = a;
        }
        __syncthreads();
        if (tid < 14) {
            int half = tid / 7, n = tid - 7 * (tid / 7);
            float s2 = 0.f;
            for (int s = 0; s < Sq; s++) s2 += M[half * 301 + s * 7 + n];
            SS[tid] = s2;
        }
        __syncthreads();
        for (int m = tid; m < 602; m += 64) Mw[m] = M[m];
        for (int m = tid; m < 896; m += 64) {
            int i = m / 7, n = m - 7 * i;
            PS1[m] = cc2[n] + ll2b[i] * SS[n];
            QS2[m] = cc2[7 + n] + ll2b[i] * SS[7 + n] + flb[n];
        }
        return;
    }

    int row = blockIdx.x * 64 + tid;
    float y[Dm];
    #pragma unroll
    for (int d = 0; d < Dm; d++) {
        y[d] = src[(size_t)row * Dm + d];
        xg[(size_t)row * Dm + d] = y[d];
    }
    ln_qkv_write(row, y, 0, Wq, bq, Wk, bk, Wv, bv, ln1a, ln1b, qb, kb, vb);
}

// ---------------------------------------------------------------------------
// k_attn: 768 blocks = (b,h), 64 threads. K/V head-slices staged to LDS
// (padded to 8 for float4 reads). One-pass softmax (no max shift; scores
// are O(0.3) so exp is safe; masked -> exp(-1e9) = 0). Writes o head-slice.
// ---------------------------------------------------------------------------
__global__ __launch_bounds__(64) void k_attn(
    const float* __restrict__ qb, const float* __restrict__ kb,
    const float* __restrict__ vb, const int* __restrict__ maskg,
    float* __restrict__ ob)
{
    __shared__ __align__(16) float ks[Sq * 8];
    __shared__ __align__(16) float vs2[Sq * 8];
    __shared__ int ms[Sq];

    const int bh = blockIdx.x;
    const int b  = bh / 3;
    const int h  = bh - 3 * b;
    const int tid = threadIdx.x;
    const size_t base = (size_t)b * Sq * Dm + h * 6;
    const float scale = 0.40824829046386296f;  // 1/sqrt(6)

    for (int e = tid; e < Sq * 6; e += 64) {
        int r = e / 6, d = e - 6 * r;
        ks[r * 8 + d]  = kb[base + (size_t)r * Dm + d];
        vs2[r * 8 + d] = vb[base + (size_t)r * Dm + d];
    }
    if (tid < Sq) ms[tid] = maskg[b * Sq + tid];
    __syncthreads();

    if (tid < Sq) {
        float qv[6];
        #pragma unroll
        for (int d = 0; d < 6; d++) qv[d] = qb[base + (size_t)tid * Dm + d];

        float sum = 0.f;
        float o6[6];
        #pragma unroll
        for (int d = 0; d < 6; d++) o6[d] = 0.f;

        for (int j = 0; j < Sq; j++) {
            const float4 k0 = *(const float4*)(ks + j * 8);
            const float  k4 = ks[j * 8 + 4], k5 = ks[j * 8 + 5];
            float t = qv[0] * k0.x + qv[1] * k0.y + qv[2] * k0.z +
                      qv[3] * k0.w + qv[4] * k4 + qv[5] * k5;
            t *= scale;
            if (ms[j] == 0) t = -1e9f;
            float e = __expf(t);
            sum += e;
            const float4 v0 = *(const float4*)(vs2 + j * 8);
            o6[0] += e * v0.x; o6[1] += e * v0.y;
            o6[2] += e * v0.z; o6[3] += e * v0.w;
            o6[4] += e * vs2[j * 8 + 4]; o6[5] += e * vs2[j * 8 + 5];
        }
        float inv = 1.f / sum;
        #pragma unroll
        for (int d = 0; d < 6; d++)
            ob[base + (size_t)tid * Dm + d] = o6[d] * inv;
    }
}

// ---------------------------------------------------------------------------
// k_mid: row-parallel (172 x 64): o-proj + residual -> y; xn = y + b2 (seed);
// x2g = LN2(y).
// ---------------------------------------------------------------------------
__global__ __launch_bounds__(64) void k_mid(
    int layer, const float* __restrict__ ob, const float* __restrict__ xg,
    float* __restrict__ xn, float* __restrict__ x2g,
    const float* __restrict__ Wo, const float* __restrict__ bo,
    const float* __restrict__ ln2a, const float* __restrict__ ln2b,
    const float* __restrict__ b2g)
{
    const int row = blockIdx.x * 64 + threadIdx.x;
    float o[Dm];
    #pragma unroll
    for (int d = 0; d < Dm; d++) o[d] = ob[(size_t)row * Dm + d];
    const float* wo = Wo + layer * Dm * Dm;
    float y[Dm];
    #pragma unroll 3
    for (int d = 0; d < Dm; d++) {
        float t = bo[layer * Dm + d];
        #pragma unroll
        for (int dd = 0; dd < Dm; dd++) t += o[dd] * wo[dd * Dm + d];
        y[d] = xg[(size_t)row * Dm + d] + t;
    }
    #pragma unroll
    for (int d = 0; d < Dm; d++)
        xn[(size_t)row * Dm + d] = y[d] + b2g[layer * Dm + d];
    float mu = 0.f;
    #pragma unroll
    for (int d = 0; d < Dm; d++) mu += y[d];
    mu *= (1.f / Dm);
    float var = 0.f;
    #pragma unroll
    for (int d = 0; d < Dm; d++) { float t = y[d] - mu; var += t * t; }
    var *= (1.f / (Dm - 1));
    float isd = 1.f / (sqrtf(var) + EPSf);
    #pragma unroll
    for (int d = 0; d < Dm; d++)
        x2g[(size_t)row * Dm + d] =
            ln2a[layer * Dm + d] * (y[d] - mu) * isd + ln2b[layer * Dm + d];
}

// ---------------------------------------------------------------------------
// k_ffn: 1376 blocks = 172 row-groups x 8 j-chunks (256 j, 2 sub-chunks of
// 128). 256 thr = 4 waves. No scalar-pipe weight traffic:
//   phase1 thread=j: W1 column via per-lane coalesced global loads, x-tile
//          broadcast from padded LDS, H -> LDS (+1 pad).
//   phase2 lane=row: H per-lane (2-way, free), W2 rows broadcast from padded
//          LDS via float4.
// Partials to P[8]; k_post sums.
// ---------------------------------------------------------------------------
__global__ __launch_bounds__(256) void k_ffn(
    int layer, const float* __restrict__ x2g,
    const float* __restrict__ W1g, const float* __restrict__ b1g,
    const float* __restrict__ W2g, float* __restrict__ P)
{
    __shared__ __align__(16) float xs[64 * 20];     // 5 KB (rows padded to 20)
    __shared__ __align__(16) float W2s[128 * 20];   // 10 KB
    __shared__ float Hs[64 * 129];                  // 33 KB (+1 pad)

    const int tid  = threadIdx.x;
    const int lane = tid & 63;
    const int wv   = __builtin_amdgcn_readfirstlane(tid >> 6);
    const int rg   = blockIdx.x >> 3;     // 0..171
    const int jcb  = blockIdx.x & 7;      // 0..7
    const int row0 = rg * 64;

    const float* W1l = W1g + (size_t)layer * Dm * Dff;
    const float* W2l = W2g + (size_t)layer * Dff * Dm;
    const float* b1l = b1g + layer * Dff;

    // stage x tile (pad 18 -> 20)
    for (int e = tid; e < 1152; e += 256) {
        int r = e / 18, d = e - r * 18;
        xs[r * 20 + d] = x2g[(size_t)row0 * Dm + e];
    }

    const int jl = tid & 127;
    const int rh = tid >> 7;              // 0 or 1 (wave-uniform)

    float acc[Dm];
    #pragma unroll
    for (int d = 0; d < Dm; d++) acc[d] = 0.f;

    for (int cc = 0; cc < 2; cc++) {
        const int j0 = jcb * 256 + cc * 128;
        // W1 column for j = j0 + jl : coalesced per-lane vector loads
        float w1[Dm];
        #pragma unroll
        for (int d = 0; d < Dm; d++) w1[d] = W1l[d * Dff + j0 + jl];
        const float b1j = b1l[j0 + jl];

        __syncthreads();   // xs staged (cc=0); W2s/Hs readers done (cc=1)
        for (int e = tid; e < 2304; e += 256) {
            int jj = e / 18;
            W2s[jj * 20 + (e - jj * 18)] = W2l[(size_t)j0 * Dm + e];
        }
        __syncthreads();

        // ---- phase 1: h for 32 rows (this thread's j) ----
        for (int r = 0; r < 32; r++) {
            const int rr = rh * 32 + r;                    // wave-uniform
            const float* xr = xs + rr * 20;
            const float4 x0 = *(const float4*)(xr);
            const float4 x1 = *(const float4*)(xr + 4);
            const float4 x2v = *(const float4*)(xr + 8);
            const float4 x3 = *(const float4*)(xr + 12);
            float hsum = b1j
                + x0.x * w1[0]  + x0.y * w1[1]  + x0.z * w1[2]  + x0.w * w1[3]
                + x1.x * w1[4]  + x1.y * w1[5]  + x1.z * w1[6]  + x1.w * w1[7]
                + x2v.x * w1[8] + x2v.y * w1[9] + x2v.z * w1[10]+ x2v.w * w1[11]
                + x3.x * w1[12] + x3.y * w1[13] + x3.z * w1[14] + x3.w * w1[15]
                + xr[16] * w1[16] + xr[17] * w1[17];
            Hs[rr * 129 + jl] = fmaxf(hsum, 0.f);
        }
        __syncthreads();

        // ---- phase 2: lane = row, wave's 32 k's ----
        for (int kk = 0; kk < 32; kk++) {
            const int kl = wv * 32 + kk;                   // wave-uniform
            const float hv = Hs[lane * 129 + kl];
            const float* wr = W2s + kl * 20;
            const float4 a0 = *(const float4*)(wr);
            const float4 a1 = *(const float4*)(wr + 4);
            const float4 a2 = *(const float4*)(wr + 8);
            const float4 a3 = *(const float4*)(wr + 12);
            acc[0]  += hv * a0.x;  acc[1]  += hv * a0.y;
            acc[2]  += hv * a0.z;  acc[3]  += hv * a0.w;
            acc[4]  += hv * a1.x;  acc[5]  += hv * a1.y;
            acc[6]  += hv * a1.z;  acc[7]  += hv * a1.w;
            acc[8]  += hv * a2.x;  acc[9]  += hv * a2.y;
            acc[10] += hv * a2.z;  acc[11] += hv * a2.w;
            acc[12] += hv * a3.x;  acc[13] += hv * a3.y;
            acc[14] += hv * a3.z;  acc[15] += hv * a3.w;
            acc[16] += hv * wr[16]; acc[17] += hv * wr[17];
        }
    }

    __syncthreads();
    #pragma unroll
    for (int d = 0; d < Dm; d++)
        Hs[(wv * 64 + lane) * Dm + d] = acc[d];            // 4608 <= 8256
    __syncthreads();
    for (int e = tid; e < 1152; e += 256) {
        float s = Hs[e] + Hs[1152 + e] + Hs[2304 + e] + Hs[3456 + e];
        P[(size_t)jcb * RSZ + (size_t)rg * 1152 + e] = s;
    }
}

// ---------------------------------------------------------------------------
// k_post: x = seed + sum of 8 partials; then LN1+QKV for next layer.
// ---------------------------------------------------------------------------
__global__ __launch_bounds__(64) void k_post(
    int layer, float* __restrict__ xn, const float* __restrict__ P,
    int do_tail,
    const float* __restrict__ Wq, const float* __restrict__ bq,
    const float* __restrict__ Wk, const float* __restrict__ bk,
    const float* __restrict__ Wv, const float* __restrict__ bv,
    const float* __restrict__ ln1a, const float* __restrict__ ln1b,
    float* __restrict__ qb, float* __restrict__ kb, float* __restrict__ vb)
{
    const int row = blockIdx.x * 64 + threadIdx.x;
    float y[Dm];
    #pragma unroll
    for (int d = 0; d < Dm; d++) {
        size_t o = (size_t)row * Dm + d;
        float t = xn[o];
        #pragma unroll
        for (int c = 0; c < JC; c++) t += P[(size_t)c * RSZ + o];
        y[d] = t;
        xn[o] = t;
    }
    if (do_tail)
        ln_qkv_write(row, y, layer + 1, Wq, bq, Wk, bk, Wv, bv,
                     ln1a, ln1b, qb, kb, vb);
}

// ---------------------------------------------------------------------------
// k_out: (i-chunk, batch) blocks; float4 stores of the 117 MB output.
// ---------------------------------------------------------------------------
__global__ __launch_bounds__(256) void k_out(
    const float* __restrict__ xg, const float* __restrict__ ll2W,
    const float* __restrict__ Mw, const float* __restrict__ PS1,
    const float* __restrict__ QS2, float* __restrict__ out)
{
    __shared__ float xb[Sq * Dm];
    __shared__ float M[602];
    __shared__ float T[2][Dm][Nb];
    __shared__ float Pc[32 * Nb];
    __shared__ float QBs[Am * Nb];

    const int b = blockIdx.y, chunk = blockIdx.x, tid = threadIdx.x;

    for (int e = tid; e < Sq * Dm; e += 256) xb[e] = xg[(size_t)b * (Sq * Dm) + e];
    for (int m = tid; m < 602; m += 256) M[m] = Mw[m];
    __syncthreads();

    for (int m = tid; m < 252; m += 256) {
        int half = m / 126, rem = m - half * 126;
        int d = rem / 7, n = rem - 7 * d;
        float a = 0.f;
        for (int s = 0; s < Sq; s++)
            a += xb[s * Dm + d] * M[half * 301 + s * 7 + n];
        T[half][d][n] = a;
    }
    __syncthreads();

    for (int m = tid; m < 224; m += 256) {
        int il = m / 7, n = m - 7 * il;
        int i = chunk * 32 + il;
        float a = PS1[i * 7 + n];
        #pragma unroll
        for (int d = 0; d < Dm; d++) a += T[0][d][n] * ll2W[d * Am + i];
        Pc[m] = a;
    }
    for (int e = tid; e < 896; e += 256) {
        int jj = e / 7, n = e - 7 * jj;
        float a = QS2[e];
        #pragma unroll
        for (int d = 0; d < Dm; d++) a += T[1][d][n] * ll2W[d * Am + jj];
        QBs[e] = a;
    }
    __syncthreads();

    if (tid < 224) {
        const int e = 4 * tid;
        const float q0 = QBs[e], q1 = QBs[e + 1], q2 = QBs[e + 2], q3 = QBs[e + 3];
        const int n0 = e % 7, n1 = (e + 1) % 7, n2 = (e + 2) % 7, n3 = (e + 3) % 7;
        const size_t base = (size_t)b * (Am * Am * Nb)
                          + (size_t)chunk * 32 * 896 + e;
        for (int il = 0; il < 32; il++) {
            const float* pc = Pc + il * 7;
            float4 v;
            v.x = pc[n0] + q0; v.y = pc[n1] + q1;
            v.z = pc[n2] + q2; v.w = pc[n3] + q3;
            *(float4*)(out + base + (size_t)il * 896) = v;
        }
    }
}

} // namespace

// ---------------------------------------------------------------------------
extern "C" void kernel_launch(void* const* d_in, const int* in_sizes, int n_in,
                              void* d_out, int out_size, void* d_ws, size_t ws_size,
                              hipStream_t stream)
{
    (void)in_sizes; (void)n_in; (void)out_size; (void)ws_size;

    const float* src  = (const float*)d_in[0];
    const int*   mask = (const int*)  d_in[1];
    const float* Wq   = (const float*)d_in[3];
    const float* bq   = (const float*)d_in[4];
    const float* Wk   = (const float*)d_in[5];
    const float* bk   = (const float*)d_in[6];
    const float* Wv   = (const float*)d_in[7];
    const float* bv   = (const float*)d_in[8];
    const float* Wo   = (const float*)d_in[9];
    const float* bo   = (const float*)d_in[10];
    const float* ln1a = (const float*)d_in[11];
    const float* ln1b = (const float*)d_in[12];
    const float* ln2a = (const float*)d_in[13];
    const float* ln2b = (const float*)d_in[14];
    const float* fW1  = (const float*)d_in[15];
    const float* fb1  = (const float*)d_in[16];
    const float* fW2  = (const float*)d_in[17];
    const float* fb2  = (const float*)d_in[18];
    const float* ll2W = (const float*)d_in[19];
    const float* ll2b = (const float*)d_in[20];
    const float* llW  = (const float*)d_in[21];
    const float* llb  = (const float*)d_in[22];
    const float* flW  = (const float*)d_in[23];
    const float* flb  = (const float*)d_in[24];
    float* out = (float*)d_out;

    float* ws  = (float*)d_ws;
    float* xA  = ws;
    float* xB  = ws + 1 * (size_t)RSZ;
    float* x2g = ws + 2 * (size_t)RSZ;
    float* qb  = ws + 3 * (size_t)RSZ;
    float* kb  = ws + 4 * (size_t)RSZ;
    float* vb  = ws + 5 * (size_t)RSZ;
    float* ob  = ws + 6 * (size_t)RSZ;
    float* P   = ws + 7 * (size_t)RSZ;        // 8 x RSZ partials
    float* Mw  = ws + (7 + JC) * (size_t)RSZ; // 602 (pad 604)
    float* PS1 = Mw + 604;
    float* QS2 = PS1 + 896;                   // total ~11.9 MB

    k_init<<<173, 64, 0, stream>>>(src, xA, Wq, bq, Wk, bk, Wv, bv,
                                   ln1a, ln1b, qb, kb, vb,
                                   llW, llb, flW, flb, ll2b, Mw, PS1, QS2);
    for (int i = 0; i < 6; i++) {
        const float* Xi = (i % 2 == 0) ? xA : xB;
        float*       Xn = (i % 2 == 0) ? xB : xA;
        k_attn<<<768, 64, 0, stream>>>(qb, kb, vb, mask, ob);
        k_mid<<<172, 64, 0, stream>>>(i, ob, Xi, Xn, x2g,
                                      Wo, bo, ln2a, ln2b, fb2);
        k_ffn<<<1376, 256, 0, stream>>>(i, x2g, fW1, fb1, fW2, P);
        k_post<<<172, 64, 0, stream>>>(i, Xn, P, (i < 5) ? 1 : 0,
                                       Wq, bq, Wk, bk, Wv, bv,
                                       ln1a, ln1b, qb, kb, vb);
    }
    k_out<<<dim3(4, 256), 256, 0, stream>>>(xA, ll2W, Mw, PS1, QS2, out);
}

// Round 5
// 604.208 us; speedup vs baseline: 2.6196x; 2.6196x over previous
//
#include <hip/hip_runtime.h>
#include <math.h>

namespace {

constexpr int Sq = 43;
constexpr int Dm = 18;
constexpr int Dff = 2048;
constexpr int Am = 128;
constexpr int Nb = 7;
constexpr int NR = 11008;          // B*SEQ rows
constexpr int RSZ = NR * Dm;       // 198144 floats
constexpr int JC = 8;              // j-chunks in FFN (256 j each)
constexpr int WROW = 20;           // padded weight row (18 w + b1 + pad)
constexpr float EPSf = 1e-6f;

// ---------------------------------------------------------------------------
// LN1 + QKV projection for one row (y[18] in registers), writes q/k/v rows.
// ---------------------------------------------------------------------------
__device__ __forceinline__ void ln_qkv_write(
    int row, const float* y, int ly,
    const float* __restrict__ Wq, const float* __restrict__ bq,
    const float* __restrict__ Wk, const float* __restrict__ bk,
    const float* __restrict__ Wv, const float* __restrict__ bv,
    const float* __restrict__ ln1a, const float* __restrict__ ln1b,
    float* __restrict__ qb, float* __restrict__ kb, float* __restrict__ vb)
{
    float mu = 0.f;
    #pragma unroll
    for (int d = 0; d < Dm; d++) mu += y[d];
    mu *= (1.f / Dm);
    float var = 0.f;
    #pragma unroll
    for (int d = 0; d < Dm; d++) { float t = y[d] - mu; var += t * t; }
    var *= (1.f / (Dm - 1));                 // ddof=1
    float isd = 1.f / (sqrtf(var) + EPSf);   // eps on sd
    float x2[Dm];
    #pragma unroll
    for (int d = 0; d < Dm; d++)
        x2[d] = ln1a[ly * Dm + d] * (y[d] - mu) * isd + ln1b[ly * Dm + d];
    const float* wq = Wq + ly * Dm * Dm;
    const float* wk = Wk + ly * Dm * Dm;
    const float* wv = Wv + ly * Dm * Dm;
    #pragma unroll 3
    for (int d = 0; d < Dm; d++) {
        float aq = bq[ly * Dm + d];
        float ak = bk[ly * Dm + d];
        float av = bv[ly * Dm + d];
        #pragma unroll
        for (int dd = 0; dd < Dm; dd++) {
            aq += x2[dd] * wq[dd * Dm + d];
            ak += x2[dd] * wk[dd * Dm + d];
            av += x2[dd] * wv[dd * Dm + d];
        }
        qb[(size_t)row * Dm + d] = aq;
        kb[(size_t)row * Dm + d] = ak;
        vb[(size_t)row * Dm + d] = av;
    }
}

// ---------------------------------------------------------------------------
// k_wprep: pack FFN weights into padded 20-float rows (16B-aligned):
//   W1P[l][j][0..17] = W1[l][d][j] (transposed), [18] = b1[l][j], [19] = 0
//   W2P[l][j][0..17] = W2[l][j][d],              [18..19] = 0
// One zero pad-row at the very end of each array (prefetch overrun guard).
// ---------------------------------------------------------------------------
__global__ __launch_bounds__(256) void k_wprep(
    const float* __restrict__ W1g, const float* __restrict__ b1g,
    const float* __restrict__ W2g,
    float* __restrict__ W1P, float* __restrict__ W2P)
{
    const int idx = blockIdx.x * 256 + threadIdx.x;   // 48 blocks * 256 = 6*2048
    const int l = idx / Dff;
    const int j = idx - l * Dff;
    float* o1 = W1P + (size_t)idx * WROW;
    float* o2 = W2P + (size_t)idx * WROW;
    #pragma unroll
    for (int d = 0; d < Dm; d++)
        o1[d] = W1g[(size_t)l * Dm * Dff + (size_t)d * Dff + j];
    o1[18] = b1g[l * Dff + j];
    o1[19] = 0.f;
    #pragma unroll
    for (int d = 0; d < Dm; d++)
        o2[d] = W2g[((size_t)l * Dff + j) * Dm + d];
    o2[18] = 0.f;
    o2[19] = 0.f;
    if (idx < WROW) {
        W1P[(size_t)6 * Dff * WROW + idx] = 0.f;
        W2P[(size_t)6 * Dff * WROW + idx] = 0.f;
    }
}

// ---------------------------------------------------------------------------
// k_init: blocks 0..171 = rows (64 each); block 172 = tail precompute (prep).
// ---------------------------------------------------------------------------
__global__ __launch_bounds__(64) void k_init(
    const float* __restrict__ src, float* __restrict__ xg,
    const float* __restrict__ Wq, const float* __restrict__ bq,
    const float* __restrict__ Wk, const float* __restrict__ bk,
    const float* __restrict__ Wv, const float* __restrict__ bv,
    const float* __restrict__ ln1a, const float* __restrict__ ln1b,
    float* __restrict__ qb, float* __restrict__ kb, float* __restrict__ vb,
    const float* __restrict__ llW, const float* __restrict__ llb,
    const float* __restrict__ flW, const float* __restrict__ flb,
    const float* __restrict__ ll2b,
    float* __restrict__ Mw, float* __restrict__ PS1, float* __restrict__ QS2)
{
    __shared__ float M[602];
    __shared__ float cc2[14];
    __shared__ float SS[14];
    const int tid = threadIdx.x;

    if (blockIdx.x == 172) {
        for (int m = tid; m < 602; m += 64) {
            int half = m / 301, rem = m - half * 301;
            int s = rem / 7, n = rem - 7 * s;
            float a = 0.f;
            for (int jj = 0; jj < Am; jj++)
                a += llW[s * Am + jj] * flW[(half * Am + jj) * Nb + n];
            M[m] = a;
        }
        if (tid < 14) {
            int half = tid / 7, n = tid - 7 * (tid / 7);
            float a = 0.f;
            for (int jj = 0; jj < Am; jj++)
                a += llb[jj] * flW[(half * Am + jj) * Nb + n];
            cc2[tid] = a;
        }
        __syncthreads();
        if (tid < 14) {
            int half = tid / 7, n = tid - 7 * (tid / 7);
            float s2 = 0.f;
            for (int s = 0; s < Sq; s++) s2 += M[half * 301 + s * 7 + n];
            SS[tid] = s2;
        }
        __syncthreads();
        for (int m = tid; m < 602; m += 64) Mw[m] = M[m];
        for (int m = tid; m < 896; m += 64) {
            int i = m / 7, n = m - 7 * i;
            PS1[m] = cc2[n] + ll2b[i] * SS[n];
            QS2[m] = cc2[7 + n] + ll2b[i] * SS[7 + n] + flb[n];
        }
        return;
    }

    int row = blockIdx.x * 64 + tid;
    float y[Dm];
    #pragma unroll
    for (int d = 0; d < Dm; d++) {
        y[d] = src[(size_t)row * Dm + d];
        xg[(size_t)row * Dm + d] = y[d];
    }
    ln_qkv_write(row, y, 0, Wq, bq, Wk, bk, Wv, bv, ln1a, ln1b, qb, kb, vb);
}

// ---------------------------------------------------------------------------
// k_attn: 256 blocks = batch, 64 threads, lane = query (<43).
// K/V staged to LDS (rows padded to 20). One-pass softmax (scores O(0.3),
// exp-safe; verified passing in R4). All 3 heads per lane, so o[18] stays
// in-thread -> fused o-proj + residual + LN2 + next-x seed (no k_mid).
// ---------------------------------------------------------------------------
__global__ __launch_bounds__(64) void k_attn(
    int layer,
    const float* __restrict__ qb, const float* __restrict__ kb,
    const float* __restrict__ vb, const int* __restrict__ maskg,
    const float* __restrict__ xg, float* __restrict__ xn,
    float* __restrict__ x2g,
    const float* __restrict__ Wo, const float* __restrict__ bo,
    const float* __restrict__ ln2a, const float* __restrict__ ln2b,
    const float* __restrict__ b2g)
{
    __shared__ __align__(16) float ks[Sq * 20];
    __shared__ __align__(16) float vs[Sq * 20];
    __shared__ int ms[Sq];

    const int b = blockIdx.x;
    const int tid = threadIdx.x;
    const float scale = 0.40824829046386296f;  // 1/sqrt(6)

    for (int e = tid; e < Sq * Dm; e += 64) {
        int r = e / 18, d = e - 18 * r;
        ks[r * 20 + d] = kb[(size_t)b * (Sq * Dm) + e];
        vs[r * 20 + d] = vb[(size_t)b * (Sq * Dm) + e];
    }
    if (tid < Sq) ms[tid] = maskg[b * Sq + tid];
    __syncthreads();

    if (tid >= Sq) return;
    const int row = b * Sq + tid;

    float qv[Dm];
    #pragma unroll
    for (int d = 0; d < Dm; d++) qv[d] = qb[(size_t)row * Dm + d];

    float o[Dm];
    #pragma unroll
    for (int h = 0; h < 3; h++) {
        float sum = 0.f;
        float o6[6];
        #pragma unroll
        for (int d = 0; d < 6; d++) o6[d] = 0.f;
        const float q0 = qv[h * 6], q1 = qv[h * 6 + 1], q2 = qv[h * 6 + 2];
        const float q3 = qv[h * 6 + 3], q4 = qv[h * 6 + 4], q5 = qv[h * 6 + 5];
        for (int j = 0; j < Sq; j++) {
            const float* kr = ks + j * 20 + h * 6;   // 8B-aligned
            const float2 k0 = *(const float2*)(kr);
            const float2 k1 = *(const float2*)(kr + 2);
            const float2 k2 = *(const float2*)(kr + 4);
            float t = q0 * k0.x + q1 * k0.y + q2 * k1.x +
                      q3 * k1.y + q4 * k2.x + q5 * k2.y;
            t *= scale;
            if (ms[j] == 0) t = -1e9f;
            float e = __expf(t);
            sum += e;
            const float* vr = vs + j * 20 + h * 6;
            const float2 v0 = *(const float2*)(vr);
            const float2 v1 = *(const float2*)(vr + 2);
            const float2 v2 = *(const float2*)(vr + 4);
            o6[0] += e * v0.x; o6[1] += e * v0.y; o6[2] += e * v1.x;
            o6[3] += e * v1.y; o6[4] += e * v2.x; o6[5] += e * v2.y;
        }
        float inv = 1.f / sum;
        #pragma unroll
        for (int d = 0; d < 6; d++) o[h * 6 + d] = o6[d] * inv;
    }

    // o-proj + residual + seed + LN2 (former k_mid, in-thread)
    const float* wo = Wo + layer * Dm * Dm;
    float y[Dm];
    #pragma unroll 3
    for (int d = 0; d < Dm; d++) {
        float t = bo[layer * Dm + d];
        #pragma unroll
        for (int dd = 0; dd < Dm; dd++) t += o[dd] * wo[dd * Dm + d];
        y[d] = xg[(size_t)row * Dm + d] + t;
    }
    #pragma unroll
    for (int d = 0; d < Dm; d++)
        xn[(size_t)row * Dm + d] = y[d] + b2g[layer * Dm + d];
    float mu = 0.f;
    #pragma unroll
    for (int d = 0; d < Dm; d++) mu += y[d];
    mu *= (1.f / Dm);
    float var = 0.f;
    #pragma unroll
    for (int d = 0; d < Dm; d++) { float t = y[d] - mu; var += t * t; }
    var *= (1.f / (Dm - 1));
    float isd = 1.f / (sqrtf(var) + EPSf);
    #pragma unroll
    for (int d = 0; d < Dm; d++)
        x2g[(size_t)row * Dm + d] =
            ln2a[layer * Dm + d] * (y[d] - mu) * isd + ln2b[layer * Dm + d];
}

// ---------------------------------------------------------------------------
// k_ffn: 1376 blocks = 172 row-groups x 8 j-chunks; 256 thr = 4 waves.
// lane = row, wave = 64-j slice. Per j: both padded weight rows arrive as
// 10 aligned float4 BROADCAST vector loads (wave-uniform address -> L1,
// no scalar pipe, no LDS), hand-prefetched one j ahead. h = relu(x.W1col+b1)
// never leaves the thread: acc[d] += h * W2row[d]. No barriers in the loop.
// Register budget ~116 live VGPRs; launch_bounds(256,3) caps allocation to
// avoid the R4 spill disaster (VGPR=256, 385 MB scratch traffic).
// ---------------------------------------------------------------------------
__global__ __launch_bounds__(256, 3) void k_ffn(
    int layer, const float* __restrict__ x2g,
    const float* __restrict__ W1P, const float* __restrict__ W2P,
    float* __restrict__ P)
{
    __shared__ float Ls[4 * 64 * Dm];   // 18 KiB (final reduce only)

    const int tid  = threadIdx.x;
    const int lane = tid & 63;
    const int wv   = __builtin_amdgcn_readfirstlane(tid >> 6);
    const int rg   = blockIdx.x >> 3;     // 0..171
    const int q    = blockIdx.x & 7;      // 0..7
    const int row  = rg * 64 + lane;
    const int j0   = q * 256 + wv * 64;

    const float4* w1p = (const float4*)(W1P + ((size_t)layer * Dff + j0) * WROW);
    const float4* w2p = (const float4*)(W2P + ((size_t)layer * Dff + j0) * WROW);

    float x[Dm];
    #pragma unroll
    for (int k = 0; k < 9; k++) {
        float2 t = *(const float2*)(x2g + (size_t)row * Dm + 2 * k);
        x[2 * k] = t.x; x[2 * k + 1] = t.y;
    }
    float acc[Dm];
    #pragma unroll
    for (int d = 0; d < Dm; d++) acc[d] = 0.f;

    float4 a0 = w1p[0], a1 = w1p[1], a2 = w1p[2], a3 = w1p[3], a4 = w1p[4];
    float4 c0 = w2p[0], c1 = w2p[1], c2 = w2p[2], c3 = w2p[3], c4 = w2p[4];

    for (int jj = 0; jj < 64; jj++) {
        const float4* n1 = w1p + (jj + 1) * 5;     // pad row guards j=2048
        const float4* n2 = w2p + (jj + 1) * 5;
        const float4 na0 = n1[0], na1 = n1[1], na2 = n1[2], na3 = n1[3], na4 = n1[4];
        const float4 nc0 = n2[0], nc1 = n2[1], nc2 = n2[2], nc3 = n2[3], nc4 = n2[4];

        float h = a4.z                                  // b1 in slot 18
            + x[0]  * a0.x + x[1]  * a0.y + x[2]  * a0.z + x[3]  * a0.w
            + x[4]  * a1.x + x[5]  * a1.y + x[6]  * a1.z + x[7]  * a1.w
            + x[8]  * a2.x + x[9]  * a2.y + x[10] * a2.z + x[11] * a2.w
            + x[12] * a3.x + x[13] * a3.y + x[14] * a3.z + x[15] * a3.w
            + x[16] * a4.x + x[17] * a4.y;
        h = fmaxf(h, 0.f);
        acc[0]  += h * c0.x;  acc[1]  += h * c0.y;
        acc[2]  += h * c0.z;  acc[3]  += h * c0.w;
        acc[4]  += h * c1.x;  acc[5]  += h * c1.y;
        acc[6]  += h * c1.z;  acc[7]  += h * c1.w;
        acc[8]  += h * c2.x;  acc[9]  += h * c2.y;
        acc[10] += h * c2.z;  acc[11] += h * c2.w;
        acc[12] += h * c3.x;  acc[13] += h * c3.y;
        acc[14] += h * c3.z;  acc[15] += h * c3.w;
        acc[16] += h * c4.x;  acc[17] += h * c4.y;

        a0 = na0; a1 = na1; a2 = na2; a3 = na3; a4 = na4;
        c0 = nc0; c1 = nc1; c2 = nc2; c3 = nc3; c4 = nc4;
    }

    #pragma unroll
    for (int d = 0; d < Dm; d++)
        Ls[(wv * 64 + lane) * Dm + d] = acc[d];
    __syncthreads();
    for (int e = tid; e < 1152; e += 256) {
        float s = Ls[e] + Ls[1152 + e] + Ls[2304 + e] + Ls[3456 + e];
        P[(size_t)q * RSZ + (size_t)rg * 1152 + e] = s;
    }
}

// ---------------------------------------------------------------------------
// k_post: x = seed + sum of 8 partials; then LN1+QKV for next layer.
// ---------------------------------------------------------------------------
__global__ __launch_bounds__(64) void k_post(
    int layer, float* __restrict__ xn, const float* __restrict__ P,
    int do_tail,
    const float* __restrict__ Wq, const float* __restrict__ bq,
    const float* __restrict__ Wk, const float* __restrict__ bk,
    const float* __restrict__ Wv, const float* __restrict__ bv,
    const float* __restrict__ ln1a, const float* __restrict__ ln1b,
    float* __restrict__ qb, float* __restrict__ kb, float* __restrict__ vb)
{
    const int row = blockIdx.x * 64 + threadIdx.x;
    float y[Dm];
    #pragma unroll
    for (int d = 0; d < Dm; d++) {
        size_t o = (size_t)row * Dm + d;
        float t = xn[o];
        #pragma unroll
        for (int c = 0; c < JC; c++) t += P[(size_t)c * RSZ + o];
        y[d] = t;
        xn[o] = t;
    }
    if (do_tail)
        ln_qkv_write(row, y, layer + 1, Wq, bq, Wk, bk, Wv, bv,
                     ln1a, ln1b, qb, kb, vb);
}

// ---------------------------------------------------------------------------
// k_out: (i-chunk, batch) blocks; float4 stores of the 117 MB output.
// ---------------------------------------------------------------------------
__global__ __launch_bounds__(256) void k_out(
    const float* __restrict__ xg, const float* __restrict__ ll2W,
    const float* __restrict__ Mw, const float* __restrict__ PS1,
    const float* __restrict__ QS2, float* __restrict__ out)
{
    __shared__ float xb[Sq * Dm];
    __shared__ float M[602];
    __shared__ float T[2][Dm][Nb];
    __shared__ float Pc[32 * Nb];
    __shared__ float QBs[Am * Nb];

    const int b = blockIdx.y, chunk = blockIdx.x, tid = threadIdx.x;

    for (int e = tid; e < Sq * Dm; e += 256) xb[e] = xg[(size_t)b * (Sq * Dm) + e];
    for (int m = tid; m < 602; m += 256) M[m] = Mw[m];
    __syncthreads();

    for (int m = tid; m < 252; m += 256) {
        int half = m / 126, rem = m - half * 126;
        int d = rem / 7, n = rem - 7 * d;
        float a = 0.f;
        for (int s = 0; s < Sq; s++)
            a += xb[s * Dm + d] * M[half * 301 + s * 7 + n];
        T[half][d][n] = a;
    }
    __syncthreads();

    for (int m = tid; m < 224; m += 256) {
        int il = m / 7, n = m - 7 * il;
        int i = chunk * 32 + il;
        float a = PS1[i * 7 + n];
        #pragma unroll
        for (int d = 0; d < Dm; d++) a += T[0][d][n] * ll2W[d * Am + i];
        Pc[m] = a;
    }
    for (int e = tid; e < 896; e += 256) {
        int jj = e / 7, n = e - 7 * jj;
        float a = QS2[e];
        #pragma unroll
        for (int d = 0; d < Dm; d++) a += T[1][d][n] * ll2W[d * Am + jj];
        QBs[e] = a;
    }
    __syncthreads();

    if (tid < 224) {
        const int e = 4 * tid;
        const float q0 = QBs[e], q1 = QBs[e + 1], q2 = QBs[e + 2], q3 = QBs[e + 3];
        const int n0 = e % 7, n1 = (e + 1) % 7, n2 = (e + 2) % 7, n3 = (e + 3) % 7;
        const size_t base = (size_t)b * (Am * Am * Nb)
                          + (size_t)chunk * 32 * 896 + e;
        for (int il = 0; il < 32; il++) {
            const float* pc = Pc + il * 7;
            float4 v;
            v.x = pc[n0] + q0; v.y = pc[n1] + q1;
            v.z = pc[n2] + q2; v.w = pc[n3] + q3;
            *(float4*)(out + base + (size_t)il * 896) = v;
        }
    }
}

} // namespace

// ---------------------------------------------------------------------------
extern "C" void kernel_launch(void* const* d_in, const int* in_sizes, int n_in,
                              void* d_out, int out_size, void* d_ws, size_t ws_size,
                              hipStream_t stream)
{
    (void)in_sizes; (void)n_in; (void)out_size; (void)ws_size;

    const float* src  = (const float*)d_in[0];
    const int*   mask = (const int*)  d_in[1];
    const float* Wq   = (const float*)d_in[3];
    const float* bq   = (const float*)d_in[4];
    const float* Wk   = (const float*)d_in[5];
    const float* bk   = (const float*)d_in[6];
    const float* Wv   = (const float*)d_in[7];
    const float* bv   = (const float*)d_in[8];
    const float* Wo   = (const float*)d_in[9];
    const float* bo   = (const float*)d_in[10];
    const float* ln1a = (const float*)d_in[11];
    const float* ln1b = (const float*)d_in[12];
    const float* ln2a = (const float*)d_in[13];
    const float* ln2b = (const float*)d_in[14];
    const float* fW1  = (const float*)d_in[15];
    const float* fb1  = (const float*)d_in[16];
    const float* fW2  = (const float*)d_in[17];
    const float* fb2  = (const float*)d_in[18];
    const float* ll2W = (const float*)d_in[19];
    const float* ll2b = (const float*)d_in[20];
    const float* llW  = (const float*)d_in[21];
    const float* llb  = (const float*)d_in[22];
    const float* flW  = (const float*)d_in[23];
    const float* flb  = (const float*)d_in[24];
    float* out = (float*)d_out;

    const size_t WPSZ = (size_t)6 * Dff * WROW + WROW;   // 245780

    float* ws  = (float*)d_ws;
    float* xA  = ws;
    float* xB  = ws + 1 * (size_t)RSZ;
    float* x2g = ws + 2 * (size_t)RSZ;
    float* qb  = ws + 3 * (size_t)RSZ;
    float* kb  = ws + 4 * (size_t)RSZ;
    float* vb  = ws + 5 * (size_t)RSZ;
    float* P   = ws + 6 * (size_t)RSZ;        // 8 x RSZ partials
    float* W1P = ws + (6 + JC) * (size_t)RSZ;
    float* W2P = W1P + WPSZ;
    float* Mw  = W2P + WPSZ;                  // 602 (pad 604)
    float* PS1 = Mw + 604;
    float* QS2 = PS1 + 896;                   // total ~13.1 MB

    k_wprep<<<48, 256, 0, stream>>>(fW1, fb1, fW2, W1P, W2P);
    k_init<<<173, 64, 0, stream>>>(src, xA, Wq, bq, Wk, bk, Wv, bv,
                                   ln1a, ln1b, qb, kb, vb,
                                   llW, llb, flW, flb, ll2b, Mw, PS1, QS2);
    for (int i = 0; i < 6; i++) {
        const float* Xi = (i % 2 == 0) ? xA : xB;
        float*       Xn = (i % 2 == 0) ? xB : xA;
        k_attn<<<256, 64, 0, stream>>>(i, qb, kb, vb, mask, Xi, Xn, x2g,
                                       Wo, bo, ln2a, ln2b, fb2);
        k_ffn<<<1376, 256, 0, stream>>>(i, x2g, W1P, W2P, P);
        k_post<<<172, 64, 0, stream>>>(i, Xn, P, (i < 5) ? 1 : 0,
                                       Wq, bq, Wk, bk, Wv, bv,
                                       ln1a, ln1b, qb, kb, vb);
    }
    k_out<<<dim3(4, 256), 256, 0, stream>>>(xA, ll2W, Mw, PS1, QS2, out);
}